// Round 11
// baseline (428.903 us; speedup 1.0000x reference)
//
#include <hip/hip_runtime.h>

#define NROWS 50000
#define MP    50048      // padded rows (multiple of 128)
#define NEDGE 800000
#define CAP   64         // max degree bucket (P[Poisson(16)>=64] ~ 1e-21)
#define ZROW  NROWS      // guaranteed-zero row used for padding slots
#define NPART (2 * (MP / 128))   // 782 partial-stat rows
#define NPARTS 391       // node partitions of 128 (391*128 = 50048)
#define PSZ   128
#define BLK_E 6144       // edges per binscatter block (262 blocks > 256 CUs)

typedef __attribute__((ext_vector_type(8))) __bf16 bf16x8;
typedef __attribute__((ext_vector_type(4))) float f32x4;
typedef unsigned short u16;
typedef unsigned int   u32;

__device__ __forceinline__ float bf2f(u16 h) {
  return __uint_as_float(((u32)h) << 16);
}
__device__ __forceinline__ u16 f2bf(float f) {
  u32 u = __float_as_uint(f);
  u += 0x7FFFu + ((u >> 16) & 1u);   // RNE (finite values only)
  return (u16)(u >> 16);
}

#define GLOAD_LDS16(g, l) \
  __builtin_amdgcn_global_load_lds((const __attribute__((address_space(1))) u32*)(g), \
                                   (__attribute__((address_space(3))) u32*)(l), 16, 0, 0)

// ---------------- weight prep: transpose to [N][K] bf16, sum Wr over types ----
__global__ void k_prep_w(const float* __restrict__ Wl, const float* __restrict__ Wr,
                         const float* __restrict__ bl, const float* __restrict__ W1,
                         const float* __restrict__ W2,
                         u16* __restrict__ WcatT, u16* __restrict__ W1T,
                         u16* __restrict__ W2T, float* __restrict__ bsum) {
  const int NW = 2 * 256 * 768;
  int i = blockIdx.x * 256 + threadIdx.x;
  if (i < NW) {
    int l = i / (256 * 768);
    int rem = i - l * (256 * 768);
    int n = rem / 768, k = rem - n * 768;
    float v;
    if (k < 256)      v = Wl[((size_t)(l * 2 + 0) * 256 + k) * 256 + n];
    else if (k < 512) v = Wl[((size_t)(l * 2 + 1) * 256 + (k - 256)) * 256 + n];
    else              v = Wr[((size_t)(l * 2 + 0) * 256 + (k - 512)) * 256 + n]
                        + Wr[((size_t)(l * 2 + 1) * 256 + (k - 512)) * 256 + n];
    WcatT[i] = f2bf(v);
  } else if (i < NW + 128 * 256) {
    int j = i - NW; int n = j >> 8, k = j & 255;
    W1T[j] = f2bf(W1[k * 128 + n]);
  } else if (i < NW + 128 * 256 + 16 * 128) {
    int j = i - NW - 128 * 256; int n = j >> 7, k = j & 127;
    W2T[j] = f2bf(W2[k * 16 + n]);
  } else if (i < NW + 128 * 256 + 16 * 128 + 512) {
    int j = i - NW - 128 * 256 - 16 * 128; int l = j >> 8, c = j & 255;
    bsum[j] = bl[(l * 2 + 0) * 256 + c] + bl[(l * 2 + 1) * 256 + c];
  }
}

// ---------------- x -> dense bf16 Xb[MP x 256] (rows >= NROWS zeroed) --------
__global__ void k_prep_x(const float* __restrict__ x, u16* __restrict__ Xb) {
  int i = blockIdx.x * 256 + threadIdx.x;   // over MP*32 (8 elems each)
  if (i >= MP * 32) return;
  int n = i >> 5, c8 = (i & 31) * 8;
  u32 w0 = 0, w1 = 0, w2 = 0, w3 = 0;
  if (n < NROWS) {
    const float* xr = x + (size_t)n * 256 + c8;
    float4 a = *reinterpret_cast<const float4*>(xr);
    float4 b = *reinterpret_cast<const float4*>(xr + 4);
    w0 = (u32)f2bf(a.x) | ((u32)f2bf(a.y) << 16);
    w1 = (u32)f2bf(a.z) | ((u32)f2bf(a.w) << 16);
    w2 = (u32)f2bf(b.x) | ((u32)f2bf(b.y) << 16);
    w3 = (u32)f2bf(b.z) | ((u32)f2bf(b.w) << 16);
  }
  *reinterpret_cast<uint4*>(Xb + (size_t)n * 256 + c8) = make_uint4(w0, w1, w2, w3);
}

// ---------------- edge binning: hist -> scan -> block-aggregated scatter -----
__global__ void k_hist(const int* __restrict__ d0, const int* __restrict__ d1,
                       int* __restrict__ hist) {
  __shared__ int h[NPARTS];
  int t = threadIdx.x;
  const int* __restrict__ d = blockIdx.y ? d1 : d0;
  for (int i = t; i < NPARTS; i += 256) h[i] = 0;
  __syncthreads();
  for (int e = blockIdx.x * 256 + t; e < NEDGE; e += gridDim.x * 256)
    atomicAdd(&h[d[e] >> 7], 1);
  __syncthreads();
  int* gh = hist + blockIdx.y * NPARTS;
  for (int i = t; i < NPARTS; i += 256)
    if (h[i]) atomicAdd(&gh[i], h[i]);
}

__global__ void k_scan(const int* __restrict__ hist, int* __restrict__ offs,
                       int* __restrict__ cursor) {
  __shared__ int sm[1024];
  int t = threadIdx.x;   // 1024 threads
  int v = (t < 2 * NPARTS) ? hist[t] : 0;
  sm[t] = v; __syncthreads();
  for (int d = 1; d < 1024; d <<= 1) {
    int xv = (t >= d) ? sm[t - d] : 0;
    __syncthreads();
    sm[t] += xv;
    __syncthreads();
  }
  if (t < 2 * NPARTS) {
    int excl = sm[t] - v;
    offs[t] = excl;
    cursor[t] = excl;
    if (t == 2 * NPARTS - 1) offs[2 * NPARTS] = sm[t];
  }
}

// Block-aggregated scatter: BLK_E edges staged in LDS, one global atomic per
// (block, partition) chunk reservation, LDS atomics for in-chunk positions.
__global__ __launch_bounds__(1024)
void k_binscatter(const int* __restrict__ s0, const int* __restrict__ d0,
                  const int* __restrict__ s1, const int* __restrict__ d1,
                  int* __restrict__ cursor, u32* __restrict__ binned) {
  __shared__ u32 epk[BLK_E];
  __shared__ int hist[NPARTS];
  const int tid = threadIdx.x;
  const int type = blockIdx.y;
  const int* __restrict__ s = type ? s1 : s0;
  const int* __restrict__ d = type ? d1 : d0;
  for (int i = tid; i < NPARTS; i += 1024) hist[i] = 0;
  __syncthreads();
  const int base = blockIdx.x * BLK_E;
#pragma unroll
  for (int k = 0; k < BLK_E / 1024; ++k) {
    int e = base + k * 1024 + tid;
    u32 pk = 0xFFFFFFFFu;
    if (e < NEDGE) {
      int dd = d[e];
      pk = ((u32)dd << 16) | (u32)s[e];       // src,dst both < 65536
      atomicAdd(&hist[dd >> 7], 1);
    }
    epk[k * 1024 + tid] = pk;
  }
  __syncthreads();
  for (int i = tid; i < NPARTS; i += 1024) {
    int h = hist[i];
    hist[i] = h ? atomicAdd(&cursor[type * NPARTS + i], h) : 0;
  }
  __syncthreads();
#pragma unroll
  for (int k = 0; k < BLK_E / 1024; ++k) {
    u32 pk = epk[k * 1024 + tid];
    if (pk != 0xFFFFFFFFu) {
      int part = pk >> 23;
      int pos = atomicAdd(&hist[part], 1);
      binned[pos] = ((pk & 0xFFFFu) << 7) | ((pk >> 16) & 127u);
    }
  }
}

// ---------------- aggregation: block per (partition, type) -------------------
// Build 128-node bucket CSR in LDS once. Per node, BOTH channel-halves are
// loaded in one batch: 8 dwordx4 gathers in flight per wave (vs 4) -> doubles
// outstanding bytes at identical working set (the r10 concurrency*latency fix).
__global__ __launch_bounds__(256)
void k_agg(const int* __restrict__ offs, const u32* __restrict__ binned,
           const u16* __restrict__ S, u16* __restrict__ A) {
  __shared__ u16 csr[PSZ * CAP];   // 16 KB
  __shared__ int cnt[PSZ];
  const int tid = threadIdx.x, lane = tid & 63, wave = tid >> 6;
  const int part = blockIdx.x, type = blockIdx.y;
  if (tid < PSZ) cnt[tid] = 0;
  __syncthreads();
  const int base = offs[type * NPARTS + part];
  const int end  = offs[type * NPARTS + part + 1];
  for (int i = base + tid; i < end; i += 256) {
    u32 pk = binned[i];
    int n = pk & 127;
    int pos = atomicAdd(&cnt[n], 1);
    if (pos < CAP) csr[n * CAP + pos] = (u16)(pk >> 7);
  }
  __syncthreads();
  const int p = lane >> 4;                 // edge-slot offset 0..3
  const int cw0 = lane & 15;               // half-0 word (ch 8*cw0..)
  const int cw1 = 16 + (lane & 15);        // half-1 word
  const uint4* __restrict__ S4 = reinterpret_cast<const uint4*>(S);
  for (int w = 0; w < 32; ++w) {
    const int n = wave * 32 + w;
    int c = cnt[n];
    if (c > CAP) c = CAP;
    int idx = (lane < c) ? (int)csr[n * CAP + lane] : ZROW;
    float a[16] = {0.f, 0.f, 0.f, 0.f, 0.f, 0.f, 0.f, 0.f,
                   0.f, 0.f, 0.f, 0.f, 0.f, 0.f, 0.f, 0.f};
    for (int e = 0; e < c; e += 16) {
      uint4 v0[4], v1[4];
#pragma unroll
      for (int u = 0; u < 4; ++u) {
        int srcn = __shfl(idx, e + u * 4 + p);
        const int rb = srcn << 5;
        v0[u] = S4[(size_t)(rb | cw0)];
        v1[u] = S4[(size_t)(rb | cw1)];
      }
#pragma unroll
      for (int u = 0; u < 4; ++u) {
        u32 w0[4] = {v0[u].x, v0[u].y, v0[u].z, v0[u].w};
        u32 w1[4] = {v1[u].x, v1[u].y, v1[u].z, v1[u].w};
#pragma unroll
        for (int j = 0; j < 4; ++j) {
          a[2 * j]         += __uint_as_float(w0[j] << 16);
          a[2 * j + 1]     += __uint_as_float(w0[j] & 0xffff0000u);
          a[8 + 2 * j]     += __uint_as_float(w1[j] << 16);
          a[8 + 2 * j + 1] += __uint_as_float(w1[j] & 0xffff0000u);
        }
      }
    }
#pragma unroll
    for (int j = 0; j < 16; ++j) {
      a[j] += __shfl_xor(a[j], 16);
      a[j] += __shfl_xor(a[j], 32);
    }
    if (lane < 16) {
      float inv = 1.0f / (float)(c > 1 ? c : 1);
      u32 o[8];
#pragma unroll
      for (int j = 0; j < 8; ++j) {
        float lo = a[2 * j] * inv, hi = a[2 * j + 1] * inv;
        u32 r;
        asm("v_cvt_pk_bf16_f32 %0, %1, %2" : "=v"(r) : "v"(lo), "v"(hi));
        o[j] = r;
      }
      u16* dst = A + (size_t)(part * PSZ + n) * 512 + type * 256 + (lane & 15) * 8;
      *reinterpret_cast<uint4*>(dst)       = make_uint4(o[0], o[1], o[2], o[3]);
      *reinterpret_cast<uint4*>(dst + 128) = make_uint4(o[4], o[5], o[6], o[7]);
    }
  }
}

// ---------------- MFMA GEMM K=768: C = [A(512) | S(256)] @ Bt^T --------------
// r5 128x128 structure; 1D grid with XCD-affinity swizzle: the two blocks
// sharing an A-tile (same bx, both N-tiles) get id%8 equal -> same XCD ->
// second A read is an L2 hit (A HBM traffic halves).
// epilogue: +bias, leaky, bf16 store (rows >= NROWS get 0), per-block col stats
__global__ __launch_bounds__(256)
void k_gemm768(const u16* __restrict__ A, const u16* __restrict__ S,
               const u16* __restrict__ Bt, const float* __restrict__ bias,
               u16* __restrict__ Cout, float* __restrict__ partial) {
  __shared__ __attribute__((aligned(16))) u16 As[128 * 32];
  __shared__ __attribute__((aligned(16))) u16 Bs[128 * 32];
  const int id = blockIdx.x;
  const int xq = id & 7;
  const int xh = (id >> 3) % 49;
  const int y  = (id >> 3) / 49;
  const int bx = xh * 8 + xq;
  if (bx >= NPARTS) return;                  // uniform early-out (2 of 784)
  const int tid = threadIdx.x, lane = tid & 63, wave = tid >> 6;
  const int wm = wave >> 1, wn = wave & 1;
  const int tileM = bx * 128, tileN = y * 128;
  f32x4 acc[4][4] = {};
  for (int k0 = 0; k0 < 768; k0 += 32) {
#pragma unroll
    for (int qq = 0; qq < 2; ++qq) {
      int idx = qq * 256 + tid;
      int row = idx >> 2, kc = idx & 3;
      const u16* ga = (k0 < 512)
          ? A + (size_t)(tileM + row) * 512 + k0 + kc * 8
          : S + (size_t)(tileM + row) * 256 + (k0 - 512) + kc * 8;
      GLOAD_LDS16(ga, As + idx * 8);
      GLOAD_LDS16(Bt + (size_t)(tileN + row) * 768 + k0 + kc * 8, Bs + idx * 8);
    }
    __syncthreads();
    bf16x8 af[4], bfr[4];
#pragma unroll
    for (int m = 0; m < 4; ++m)
      af[m] = *reinterpret_cast<const bf16x8*>(
          As + (wm * 64 + m * 16 + (lane & 15)) * 32 + (lane >> 4) * 8);
#pragma unroll
    for (int n = 0; n < 4; ++n)
      bfr[n] = *reinterpret_cast<const bf16x8*>(
          Bs + (wn * 64 + n * 16 + (lane & 15)) * 32 + (lane >> 4) * 8);
#pragma unroll
    for (int m = 0; m < 4; ++m)
#pragma unroll
      for (int n = 0; n < 4; ++n)
        acc[m][n] = __builtin_amdgcn_mfma_f32_16x16x32_bf16(af[m], bfr[n], acc[m][n], 0, 0, 0);
    __syncthreads();
  }
  const int rowbase = tileM + wm * 64;
  const int colbase = tileN + wn * 64;
#pragma unroll
  for (int n = 0; n < 4; ++n) {
    const int col = colbase + n * 16 + (lane & 15);
    const float b = bias[col];
    float s1 = 0.f, s2 = 0.f;
#pragma unroll
    for (int m = 0; m < 4; ++m) {
      const int row0 = rowbase + m * 16 + ((lane >> 4) << 2);
#pragma unroll
      for (int r = 0; r < 4; ++r) {
        const int row = row0 + r;
        float v = acc[m][n][r] + b;
        v = v > 0.f ? v : 0.1f * v;
        if (row >= NROWS) v = 0.f;             // keep ZROW (and pad) zero
        Cout[(size_t)row * 256 + col] = f2bf(v);
        if (row < NROWS) { s1 += v; s2 += v * v; }
      }
    }
    s1 += __shfl_xor(s1, 16); s2 += __shfl_xor(s2, 16);
    s1 += __shfl_xor(s1, 32); s2 += __shfl_xor(s2, 32);
    if (lane < 16) {
      float* pr = partial + (size_t)(bx * 2 + wm) * 512;
      pr[col] = s1;
      pr[256 + col] = s2;
    }
  }
}

// ---------------- reduce partials -> per-channel scale/shift -----------------
__global__ void k_stats(const float* __restrict__ partial, const float* __restrict__ gamma,
                        const float* __restrict__ beta, float* __restrict__ scsh) {
  __shared__ float sm1[256], sm2[256];
  int c = blockIdx.x, t = threadIdx.x;
  float s1 = 0.f, s2 = 0.f;
  for (int r = t; r < NPART; r += 256) {
    s1 += partial[(size_t)r * 512 + c];
    s2 += partial[(size_t)r * 512 + 256 + c];
  }
  sm1[t] = s1; sm2[t] = s2; __syncthreads();
  for (int d = 128; d; d >>= 1) {
    if (t < d) { sm1[t] += sm1[t + d]; sm2[t] += sm2[t + d]; }
    __syncthreads();
  }
  if (t == 0) {
    float mu = sm1[0] * (1.f / NROWS);
    float var = sm2[0] * (1.f / NROWS) - mu * mu;
    float sc = gamma[c] * rsqrtf(var + 1e-5f);
    scsh[c] = sc;
    scsh[256 + c] = beta[c] - mu * sc;
  }
}

// ---------------- fold BN into next-layer Wcat (in place) + bias -------------
__global__ void k_fold_cat(const float* __restrict__ scsh, const float* __restrict__ bsum,
                           u16* __restrict__ W, float* __restrict__ foldb) {
  __shared__ float sm[256];
  int n = blockIdx.x, t = threadIdx.x;
  u16* Wr = W + (size_t)n * 768;
  float sc = scsh[t], sh = scsh[256 + t];
  float acc = 0.f;
#pragma unroll
  for (int j = 0; j < 3; ++j) {
    int k = t + j * 256;
    float w = bf2f(Wr[k]);
    acc += sh * w;
    Wr[k] = f2bf(w * sc);
  }
  sm[t] = acc; __syncthreads();
  for (int d = 128; d; d >>= 1) {
    if (t < d) sm[t] += sm[t + d];
    __syncthreads();
  }
  if (t == 0) foldb[n] = bsum[256 + n] + sm[0];
}

// ---------------- fold BN into W1 (in place) + bias --------------------------
__global__ void k_fold_w1(const float* __restrict__ scsh, const float* __restrict__ b1,
                          u16* __restrict__ W1T, float* __restrict__ b1f) {
  __shared__ float sm[256];
  int n = blockIdx.x, t = threadIdx.x;
  u16* Wr = W1T + (size_t)n * 256;
  float w = bf2f(Wr[t]);
  float acc = scsh[256 + t] * w;
  Wr[t] = f2bf(w * scsh[t]);
  sm[t] = acc; __syncthreads();
  for (int d = 128; d; d >>= 1) {
    if (t < d) sm[t] += sm[t + d];
    __syncthreads();
  }
  if (t == 0) b1f[n] = b1[n] + sm[0];
}

// ---------------- fused MLP: out = leaky(S@W1'+b1f) @ W2 + b2 ----------------
__global__ __launch_bounds__(256)
void k_mlp(const u16* __restrict__ S, const u16* __restrict__ W1T,
           const float* __restrict__ b1f, const u16* __restrict__ W2T,
           const float* __restrict__ b2, float* __restrict__ out) {
  __shared__ __attribute__((aligned(16))) u16 As[128 * 32];
  __shared__ __attribute__((aligned(16))) u16 Bs[128 * 32];
  __shared__ __attribute__((aligned(16))) u16 Gs[128 * 136];
  __shared__ __attribute__((aligned(16))) u16 Ws[16 * 136];
  const int tid = threadIdx.x, lane = tid & 63, wave = tid >> 6;
  const int wm = wave >> 1, wn = wave & 1;
  const int tileM = blockIdx.x * 128;
  {  // stage W2T (16x128) into LDS
    int n = tid >> 4, k8 = (tid & 15) * 8;
    *reinterpret_cast<uint4*>(Ws + n * 136 + k8) =
        *reinterpret_cast<const uint4*>(W2T + n * 128 + k8);
  }
  f32x4 acc[4][4] = {};
  for (int k0 = 0; k0 < 256; k0 += 32) {
#pragma unroll
    for (int qq = 0; qq < 2; ++qq) {
      int idx = qq * 256 + tid;
      int row = idx >> 2, kc = idx & 3;
      GLOAD_LDS16(S + (size_t)(tileM + row) * 256 + k0 + kc * 8, As + idx * 8);
      GLOAD_LDS16(W1T + (size_t)row * 256 + k0 + kc * 8, Bs + idx * 8);
    }
    __syncthreads();
    bf16x8 af[4], bfr[4];
#pragma unroll
    for (int m = 0; m < 4; ++m)
      af[m] = *reinterpret_cast<const bf16x8*>(
          As + (wm * 64 + m * 16 + (lane & 15)) * 32 + (lane >> 4) * 8);
#pragma unroll
    for (int n = 0; n < 4; ++n)
      bfr[n] = *reinterpret_cast<const bf16x8*>(
          Bs + (wn * 64 + n * 16 + (lane & 15)) * 32 + (lane >> 4) * 8);
#pragma unroll
    for (int m = 0; m < 4; ++m)
#pragma unroll
      for (int n = 0; n < 4; ++n)
        acc[m][n] = __builtin_amdgcn_mfma_f32_16x16x32_bf16(af[m], bfr[n], acc[m][n], 0, 0, 0);
    __syncthreads();
  }
  // epilogue 1: leaky(acc + b1f) -> Gs (bf16), all 128 rows
#pragma unroll
  for (int n = 0; n < 4; ++n) {
    const int col = wn * 64 + n * 16 + (lane & 15);
    const float b = b1f[col];
#pragma unroll
    for (int m = 0; m < 4; ++m) {
      const int lr0 = wm * 64 + m * 16 + ((lane >> 4) << 2);
#pragma unroll
      for (int r = 0; r < 4; ++r) {
        float v = acc[m][n][r] + b;
        v = v > 0.f ? v : 0.1f * v;
        Gs[(lr0 + r) * 136 + col] = f2bf(v);
      }
    }
  }
  __syncthreads();
  // epilogue 2: out-tile = Gs @ Ws^T + b2  (each wave: 32 rows)
  const int rr = wave * 32;
#pragma unroll
  for (int cc = 0; cc < 2; ++cc) {
    f32x4 a2 = {};
#pragma unroll
    for (int kk = 0; kk < 4; ++kk) {
      bf16x8 af = *reinterpret_cast<const bf16x8*>(
          Gs + (rr + cc * 16 + (lane & 15)) * 136 + kk * 32 + (lane >> 4) * 8);
      bf16x8 bf = *reinterpret_cast<const bf16x8*>(
          Ws + (lane & 15) * 136 + kk * 32 + (lane >> 4) * 8);
      a2 = __builtin_amdgcn_mfma_f32_16x16x32_bf16(af, bf, a2, 0, 0, 0);
    }
    const int col = lane & 15;
    const int row0 = tileM + rr + cc * 16 + ((lane >> 4) << 2);
#pragma unroll
    for (int r = 0; r < 4; ++r) {
      int row = row0 + r;
      if (row < NROWS) out[(size_t)row * 16 + col] = a2[r] + b2[col];
    }
  }
}

// =============================================================================
extern "C" void kernel_launch(void* const* d_in, const int* in_sizes, int n_in,
                              void* d_out, int out_size, void* d_ws, size_t ws_size,
                              hipStream_t stream) {
  const float* x   = (const float*)d_in[0];
  const int* src0  = (const int*)d_in[1];
  const int* dst0  = (const int*)d_in[2];
  const int* src1  = (const int*)d_in[3];
  const int* dst1  = (const int*)d_in[4];
  const float* Wl  = (const float*)d_in[5];
  const float* bl  = (const float*)d_in[6];
  const float* Wr  = (const float*)d_in[7];
  const float* gma = (const float*)d_in[8];
  const float* bta = (const float*)d_in[9];
  const float* W1  = (const float*)d_in[10];
  const float* b1  = (const float*)d_in[11];
  const float* W2  = (const float*)d_in[12];
  const float* b2  = (const float*)d_in[13];
  float* out = (float*)d_out;
  (void)in_sizes; (void)n_in; (void)out_size; (void)ws_size;

  char* p = (char*)d_ws;
  auto take = [&](size_t bytes) -> void* {
    char* r = p; p += (bytes + 255) & ~(size_t)255; return (void*)r;
  };
  u16* Xb    = (u16*)take((size_t)MP * 256 * 2);   // x bf16; later reused as Hn1
  u16* A     = (u16*)take((size_t)MP * 512 * 2);   // [mean0 | mean1]
  u16* Hn0   = (u16*)take((size_t)MP * 256 * 2);   // layer-0 raw activation
  u16* WcatT = (u16*)take((size_t)2 * 256 * 768 * 2);
  u16* W1T   = (u16*)take(128 * 256 * 2);
  u16* W2T   = (u16*)take(16 * 128 * 2);
  float* bsum  = (float*)take(512 * 4);
  float* scsh  = (float*)take(512 * 4);
  float* foldb = (float*)take(256 * 4);
  float* b1f   = (float*)take(128 * 4);
  float* partial = (float*)take((size_t)NPART * 512 * 4);
  int* hist    = (int*)take((size_t)2 * NPARTS * 4);
  int* offs    = (int*)take((size_t)(2 * NPARTS + 1) * 4);
  int* cursor  = (int*)take((size_t)2 * NPARTS * 4);
  u32* binned  = (u32*)take((size_t)2 * NEDGE * 4);
  u16* Hn1 = Xb;   // alias: Xb free after layer-0 GEMM

  {
    int total = 2 * 256 * 768 + 128 * 256 + 16 * 128 + 512;
    k_prep_w<<<(total + 255) / 256, 256, 0, stream>>>(Wl, Wr, bl, W1, W2,
                                                      WcatT, W1T, W2T, bsum);
  }
  k_prep_x<<<(MP * 32 + 255) / 256, 256, 0, stream>>>(x, Xb);
  hipMemsetAsync(hist, 0, (size_t)2 * NPARTS * 4, stream);
  k_hist<<<dim3(128, 2), 256, 0, stream>>>(dst0, dst1, hist);
  k_scan<<<1, 1024, 0, stream>>>(hist, offs, cursor);
  k_binscatter<<<dim3((NEDGE + BLK_E - 1) / BLK_E, 2), 1024, 0, stream>>>(
      src0, dst0, src1, dst1, cursor, binned);

  // ---- layer 0
  k_agg<<<dim3(NPARTS, 2), 256, 0, stream>>>(offs, binned, Xb, A);
  k_gemm768<<<784, 256, 0, stream>>>(A, Xb, WcatT, bsum, Hn0, partial);
  k_stats<<<256, 256, 0, stream>>>(partial, gma, bta, scsh);
  k_fold_cat<<<256, 256, 0, stream>>>(scsh, bsum, WcatT + (size_t)256 * 768, foldb);

  // ---- layer 1
  k_agg<<<dim3(NPARTS, 2), 256, 0, stream>>>(offs, binned, Hn0, A);
  k_gemm768<<<784, 256, 0, stream>>>(A, Hn0, WcatT + (size_t)256 * 768,
                                     foldb, Hn1, partial);
  k_stats<<<256, 256, 0, stream>>>(partial, gma + 256, bta + 256, scsh);
  k_fold_w1<<<128, 256, 0, stream>>>(scsh, b1, W1T, b1f);

  // ---- fused MLP + output projection
  k_mlp<<<MP / 128, 256, 0, stream>>>(Hn1, W1T, b1f, W2T, b2, out);
}

// Round 12
// 387.372 us; speedup vs baseline: 1.1072x; 1.1072x over previous
//
#include <hip/hip_runtime.h>

#define NROWS 50000
#define MP    50048      // padded rows (multiple of 128)
#define NEDGE 800000
#define CAP   64         // max degree bucket (P[Poisson(16)>=64] ~ 1e-21)
#define ZROW  NROWS      // guaranteed-zero row used for padding slots
#define NPART (2 * (MP / 128))   // 782 partial-stat rows
#define NPARTS 391       // node partitions of 128 (391*128 = 50048)
#define PSZ   128
#define BLK_E 6144       // edges per binscatter block (262 blocks > 256 CUs)

typedef __attribute__((ext_vector_type(8))) __bf16 bf16x8;
typedef __attribute__((ext_vector_type(4))) float f32x4;
typedef unsigned short u16;
typedef unsigned int   u32;

__device__ __forceinline__ float bf2f(u16 h) {
  return __uint_as_float(((u32)h) << 16);
}
__device__ __forceinline__ u16 f2bf(float f) {
  u32 u = __float_as_uint(f);
  u += 0x7FFFu + ((u >> 16) & 1u);   // RNE (finite values only)
  return (u16)(u >> 16);
}

#define GLOAD_LDS16(g, l) \
  __builtin_amdgcn_global_load_lds((const __attribute__((address_space(1))) u32*)(g), \
                                   (__attribute__((address_space(3))) u32*)(l), 16, 0, 0)

// ---------------- weight prep: transpose to [N][K] bf16, sum Wr over types ----
__global__ void k_prep_w(const float* __restrict__ Wl, const float* __restrict__ Wr,
                         const float* __restrict__ bl, const float* __restrict__ W1,
                         const float* __restrict__ W2,
                         u16* __restrict__ WcatT, u16* __restrict__ W1T,
                         u16* __restrict__ W2T, float* __restrict__ bsum) {
  const int NW = 2 * 256 * 768;
  int i = blockIdx.x * 256 + threadIdx.x;
  if (i < NW) {
    int l = i / (256 * 768);
    int rem = i - l * (256 * 768);
    int n = rem / 768, k = rem - n * 768;
    float v;
    if (k < 256)      v = Wl[((size_t)(l * 2 + 0) * 256 + k) * 256 + n];
    else if (k < 512) v = Wl[((size_t)(l * 2 + 1) * 256 + (k - 256)) * 256 + n];
    else              v = Wr[((size_t)(l * 2 + 0) * 256 + (k - 512)) * 256 + n]
                        + Wr[((size_t)(l * 2 + 1) * 256 + (k - 512)) * 256 + n];
    WcatT[i] = f2bf(v);
  } else if (i < NW + 128 * 256) {
    int j = i - NW; int n = j >> 8, k = j & 255;
    W1T[j] = f2bf(W1[k * 128 + n]);
  } else if (i < NW + 128 * 256 + 16 * 128) {
    int j = i - NW - 128 * 256; int n = j >> 7, k = j & 127;
    W2T[j] = f2bf(W2[k * 16 + n]);
  } else if (i < NW + 128 * 256 + 16 * 128 + 512) {
    int j = i - NW - 128 * 256 - 16 * 128; int l = j >> 8, c = j & 255;
    bsum[j] = bl[(l * 2 + 0) * 256 + c] + bl[(l * 2 + 1) * 256 + c];
  }
}

// ---------------- x -> dense bf16 Xb[MP x 256] (rows >= NROWS zeroed) --------
__global__ void k_prep_x(const float* __restrict__ x, u16* __restrict__ Xb) {
  int i = blockIdx.x * 256 + threadIdx.x;   // over MP*32 (8 elems each)
  if (i >= MP * 32) return;
  int n = i >> 5, c8 = (i & 31) * 8;
  u32 w0 = 0, w1 = 0, w2 = 0, w3 = 0;
  if (n < NROWS) {
    const float* xr = x + (size_t)n * 256 + c8;
    float4 a = *reinterpret_cast<const float4*>(xr);
    float4 b = *reinterpret_cast<const float4*>(xr + 4);
    w0 = (u32)f2bf(a.x) | ((u32)f2bf(a.y) << 16);
    w1 = (u32)f2bf(a.z) | ((u32)f2bf(a.w) << 16);
    w2 = (u32)f2bf(b.x) | ((u32)f2bf(b.y) << 16);
    w3 = (u32)f2bf(b.z) | ((u32)f2bf(b.w) << 16);
  }
  *reinterpret_cast<uint4*>(Xb + (size_t)n * 256 + c8) = make_uint4(w0, w1, w2, w3);
}

// ---------------- edge binning: hist -> scan -> block-aggregated scatter -----
__global__ void k_hist(const int* __restrict__ d0, const int* __restrict__ d1,
                       int* __restrict__ hist) {
  __shared__ int h[NPARTS];
  int t = threadIdx.x;
  const int* __restrict__ d = blockIdx.y ? d1 : d0;
  for (int i = t; i < NPARTS; i += 256) h[i] = 0;
  __syncthreads();
  for (int e = blockIdx.x * 256 + t; e < NEDGE; e += gridDim.x * 256)
    atomicAdd(&h[d[e] >> 7], 1);
  __syncthreads();
  int* gh = hist + blockIdx.y * NPARTS;
  for (int i = t; i < NPARTS; i += 256)
    if (h[i]) atomicAdd(&gh[i], h[i]);
}

__global__ void k_scan(const int* __restrict__ hist, int* __restrict__ offs,
                       int* __restrict__ cursor) {
  __shared__ int sm[1024];
  int t = threadIdx.x;   // 1024 threads
  int v = (t < 2 * NPARTS) ? hist[t] : 0;
  sm[t] = v; __syncthreads();
  for (int d = 1; d < 1024; d <<= 1) {
    int xv = (t >= d) ? sm[t - d] : 0;
    __syncthreads();
    sm[t] += xv;
    __syncthreads();
  }
  if (t < 2 * NPARTS) {
    int excl = sm[t] - v;
    offs[t] = excl;
    cursor[t] = excl;
    if (t == 2 * NPARTS - 1) offs[2 * NPARTS] = sm[t];
  }
}

// Block-aggregated scatter: BLK_E edges staged in LDS, one global atomic per
// (block, partition) chunk reservation, LDS atomics for in-chunk positions.
__global__ __launch_bounds__(1024)
void k_binscatter(const int* __restrict__ s0, const int* __restrict__ d0,
                  const int* __restrict__ s1, const int* __restrict__ d1,
                  int* __restrict__ cursor, u32* __restrict__ binned) {
  __shared__ u32 epk[BLK_E];
  __shared__ int hist[NPARTS];
  const int tid = threadIdx.x;
  const int type = blockIdx.y;
  const int* __restrict__ s = type ? s1 : s0;
  const int* __restrict__ d = type ? d1 : d0;
  for (int i = tid; i < NPARTS; i += 1024) hist[i] = 0;
  __syncthreads();
  const int base = blockIdx.x * BLK_E;
#pragma unroll
  for (int k = 0; k < BLK_E / 1024; ++k) {
    int e = base + k * 1024 + tid;
    u32 pk = 0xFFFFFFFFu;
    if (e < NEDGE) {
      int dd = d[e];
      pk = ((u32)dd << 16) | (u32)s[e];       // src,dst both < 65536
      atomicAdd(&hist[dd >> 7], 1);
    }
    epk[k * 1024 + tid] = pk;
  }
  __syncthreads();
  for (int i = tid; i < NPARTS; i += 1024) {
    int h = hist[i];
    hist[i] = h ? atomicAdd(&cursor[type * NPARTS + i], h) : 0;
  }
  __syncthreads();
#pragma unroll
  for (int k = 0; k < BLK_E / 1024; ++k) {
    u32 pk = epk[k * 1024 + tid];
    if (pk != 0xFFFFFFFFu) {
      int part = pk >> 23;
      int pos = atomicAdd(&hist[part], 1);
      binned[pos] = ((pk & 0xFFFFu) << 7) | ((pk >> 16) & 127u);
    }
  }
}

// ---------------- aggregation: block per (partition, type) -------------------
// Build 128-node bucket CSR in LDS once, then aggregate both channel-halves.
// (round-5/10 configuration: measured fixed point — 112us, 291MB, 3.1TB/s.
//  r6 (8 waves), r7 (quarter-slice), r11 (8-deep ILP) all inflate FETCH and
//  regress: added MLP raises L2 capacity misses; fetch path saturated.)
__global__ __launch_bounds__(256)
void k_agg(const int* __restrict__ offs, const u32* __restrict__ binned,
           const u16* __restrict__ S, u16* __restrict__ A) {
  __shared__ u16 csr[PSZ * CAP];   // 16 KB
  __shared__ int cnt[PSZ];
  const int tid = threadIdx.x, lane = tid & 63, wave = tid >> 6;
  const int part = blockIdx.x, type = blockIdx.y;
  if (tid < PSZ) cnt[tid] = 0;
  __syncthreads();
  const int base = offs[type * NPARTS + part];
  const int end  = offs[type * NPARTS + part + 1];
  for (int i = base + tid; i < end; i += 256) {
    u32 pk = binned[i];
    int n = pk & 127;
    int pos = atomicAdd(&cnt[n], 1);
    if (pos < CAP) csr[n * CAP + pos] = (u16)(pk >> 7);
  }
  __syncthreads();
  const int p = lane >> 4;                     // edge-slot offset 0..3
  const uint4* __restrict__ S4 = reinterpret_cast<const uint4*>(S);
  for (int hh = 0; hh < 2; ++hh) {
    const int c8 = hh * 128 + (lane & 15) * 8;   // 8 channels
    const int cword = c8 >> 3;
    for (int w = 0; w < 32; ++w) {
      const int n = wave * 32 + w;
      int c = cnt[n];
      if (c > CAP) c = CAP;
      int idx = (lane < c) ? (int)csr[n * CAP + lane] : ZROW;
      float a[8] = {0.f, 0.f, 0.f, 0.f, 0.f, 0.f, 0.f, 0.f};
      for (int e = 0; e < c; e += 16) {
        uint4 v[4];
#pragma unroll
        for (int u = 0; u < 4; ++u) {
          int srcn = __shfl(idx, e + u * 4 + p);
          v[u] = S4[(size_t)((srcn << 5) | cword)];
        }
#pragma unroll
        for (int u = 0; u < 4; ++u) {
          u32 wd[4] = {v[u].x, v[u].y, v[u].z, v[u].w};
#pragma unroll
          for (int j = 0; j < 4; ++j) {
            a[2 * j]     += __uint_as_float(wd[j] << 16);
            a[2 * j + 1] += __uint_as_float(wd[j] & 0xffff0000u);
          }
        }
      }
#pragma unroll
      for (int j = 0; j < 8; ++j) {
        a[j] += __shfl_xor(a[j], 16);
        a[j] += __shfl_xor(a[j], 32);
      }
      if (lane < 16) {
        float inv = 1.0f / (float)(c > 1 ? c : 1);
        u32 o[4];
#pragma unroll
        for (int j = 0; j < 4; ++j) {
          float lo = a[2 * j] * inv, hi = a[2 * j + 1] * inv;
          u32 r;
          asm("v_cvt_pk_bf16_f32 %0, %1, %2" : "=v"(r) : "v"(lo), "v"(hi));
          o[j] = r;
        }
        *reinterpret_cast<uint4*>(A + (size_t)(part * PSZ + n) * 512 + type * 256 + c8) =
            make_uint4(o[0], o[1], o[2], o[3]);
      }
    }
  }
}

// ---------------- MFMA GEMM K=768: C = [A(512) | S(256)] @ Bt^T --------------
// r5 128x128 structure; 1D grid with XCD-affinity swizzle: the two blocks
// sharing an A-tile (same bx, both N-tiles) get id%8 equal -> same XCD ->
// second A read is an L2 hit (A HBM traffic halves).
// epilogue: +bias, leaky, bf16 store (rows >= NROWS get 0), per-block col stats
__global__ __launch_bounds__(256)
void k_gemm768(const u16* __restrict__ A, const u16* __restrict__ S,
               const u16* __restrict__ Bt, const float* __restrict__ bias,
               u16* __restrict__ Cout, float* __restrict__ partial) {
  __shared__ __attribute__((aligned(16))) u16 As[128 * 32];
  __shared__ __attribute__((aligned(16))) u16 Bs[128 * 32];
  const int id = blockIdx.x;
  const int xq = id & 7;
  const int xh = (id >> 3) % 49;
  const int y  = (id >> 3) / 49;
  const int bx = xh * 8 + xq;
  if (bx >= NPARTS) return;                  // uniform early-out (2 of 784)
  const int tid = threadIdx.x, lane = tid & 63, wave = tid >> 6;
  const int wm = wave >> 1, wn = wave & 1;
  const int tileM = bx * 128, tileN = y * 128;
  f32x4 acc[4][4] = {};
  for (int k0 = 0; k0 < 768; k0 += 32) {
#pragma unroll
    for (int qq = 0; qq < 2; ++qq) {
      int idx = qq * 256 + tid;
      int row = idx >> 2, kc = idx & 3;
      const u16* ga = (k0 < 512)
          ? A + (size_t)(tileM + row) * 512 + k0 + kc * 8
          : S + (size_t)(tileM + row) * 256 + (k0 - 512) + kc * 8;
      GLOAD_LDS16(ga, As + idx * 8);
      GLOAD_LDS16(Bt + (size_t)(tileN + row) * 768 + k0 + kc * 8, Bs + idx * 8);
    }
    __syncthreads();
    bf16x8 af[4], bfr[4];
#pragma unroll
    for (int m = 0; m < 4; ++m)
      af[m] = *reinterpret_cast<const bf16x8*>(
          As + (wm * 64 + m * 16 + (lane & 15)) * 32 + (lane >> 4) * 8);
#pragma unroll
    for (int n = 0; n < 4; ++n)
      bfr[n] = *reinterpret_cast<const bf16x8*>(
          Bs + (wn * 64 + n * 16 + (lane & 15)) * 32 + (lane >> 4) * 8);
#pragma unroll
    for (int m = 0; m < 4; ++m)
#pragma unroll
      for (int n = 0; n < 4; ++n)
        acc[m][n] = __builtin_amdgcn_mfma_f32_16x16x32_bf16(af[m], bfr[n], acc[m][n], 0, 0, 0);
    __syncthreads();
  }
  const int rowbase = tileM + wm * 64;
  const int colbase = tileN + wn * 64;
#pragma unroll
  for (int n = 0; n < 4; ++n) {
    const int col = colbase + n * 16 + (lane & 15);
    const float b = bias[col];
    float s1 = 0.f, s2 = 0.f;
#pragma unroll
    for (int m = 0; m < 4; ++m) {
      const int row0 = rowbase + m * 16 + ((lane >> 4) << 2);
#pragma unroll
      for (int r = 0; r < 4; ++r) {
        const int row = row0 + r;
        float v = acc[m][n][r] + b;
        v = v > 0.f ? v : 0.1f * v;
        if (row >= NROWS) v = 0.f;             // keep ZROW (and pad) zero
        Cout[(size_t)row * 256 + col] = f2bf(v);
        if (row < NROWS) { s1 += v; s2 += v * v; }
      }
    }
    s1 += __shfl_xor(s1, 16); s2 += __shfl_xor(s2, 16);
    s1 += __shfl_xor(s1, 32); s2 += __shfl_xor(s2, 32);
    if (lane < 16) {
      float* pr = partial + (size_t)(bx * 2 + wm) * 512;
      pr[col] = s1;
      pr[256 + col] = s2;
    }
  }
}

// ---------------- reduce partials -> per-channel scale/shift -----------------
__global__ void k_stats(const float* __restrict__ partial, const float* __restrict__ gamma,
                        const float* __restrict__ beta, float* __restrict__ scsh) {
  __shared__ float sm1[256], sm2[256];
  int c = blockIdx.x, t = threadIdx.x;
  float s1 = 0.f, s2 = 0.f;
  for (int r = t; r < NPART; r += 256) {
    s1 += partial[(size_t)r * 512 + c];
    s2 += partial[(size_t)r * 512 + 256 + c];
  }
  sm1[t] = s1; sm2[t] = s2; __syncthreads();
  for (int d = 128; d; d >>= 1) {
    if (t < d) { sm1[t] += sm1[t + d]; sm2[t] += sm2[t + d]; }
    __syncthreads();
  }
  if (t == 0) {
    float mu = sm1[0] * (1.f / NROWS);
    float var = sm2[0] * (1.f / NROWS) - mu * mu;
    float sc = gamma[c] * rsqrtf(var + 1e-5f);
    scsh[c] = sc;
    scsh[256 + c] = beta[c] - mu * sc;
  }
}

// ---------------- fold BN into next-layer Wcat (in place) + bias -------------
__global__ void k_fold_cat(const float* __restrict__ scsh, const float* __restrict__ bsum,
                           u16* __restrict__ W, float* __restrict__ foldb) {
  __shared__ float sm[256];
  int n = blockIdx.x, t = threadIdx.x;
  u16* Wr = W + (size_t)n * 768;
  float sc = scsh[t], sh = scsh[256 + t];
  float acc = 0.f;
#pragma unroll
  for (int j = 0; j < 3; ++j) {
    int k = t + j * 256;
    float w = bf2f(Wr[k]);
    acc += sh * w;
    Wr[k] = f2bf(w * sc);
  }
  sm[t] = acc; __syncthreads();
  for (int d = 128; d; d >>= 1) {
    if (t < d) sm[t] += sm[t + d];
    __syncthreads();
  }
  if (t == 0) foldb[n] = bsum[256 + n] + sm[0];
}

// ---------------- fold BN into W1 (in place) + bias --------------------------
__global__ void k_fold_w1(const float* __restrict__ scsh, const float* __restrict__ b1,
                          u16* __restrict__ W1T, float* __restrict__ b1f) {
  __shared__ float sm[256];
  int n = blockIdx.x, t = threadIdx.x;
  u16* Wr = W1T + (size_t)n * 256;
  float w = bf2f(Wr[t]);
  float acc = scsh[256 + t] * w;
  Wr[t] = f2bf(w * scsh[t]);
  sm[t] = acc; __syncthreads();
  for (int d = 128; d; d >>= 1) {
    if (t < d) sm[t] += sm[t + d];
    __syncthreads();
  }
  if (t == 0) b1f[n] = b1[n] + sm[0];
}

// ---------------- fused MLP: out = leaky(S@W1'+b1f) @ W2 + b2 ----------------
__global__ __launch_bounds__(256)
void k_mlp(const u16* __restrict__ S, const u16* __restrict__ W1T,
           const float* __restrict__ b1f, const u16* __restrict__ W2T,
           const float* __restrict__ b2, float* __restrict__ out) {
  __shared__ __attribute__((aligned(16))) u16 As[128 * 32];
  __shared__ __attribute__((aligned(16))) u16 Bs[128 * 32];
  __shared__ __attribute__((aligned(16))) u16 Gs[128 * 136];
  __shared__ __attribute__((aligned(16))) u16 Ws[16 * 136];
  const int tid = threadIdx.x, lane = tid & 63, wave = tid >> 6;
  const int wm = wave >> 1, wn = wave & 1;
  const int tileM = blockIdx.x * 128;
  {  // stage W2T (16x128) into LDS
    int n = tid >> 4, k8 = (tid & 15) * 8;
    *reinterpret_cast<uint4*>(Ws + n * 136 + k8) =
        *reinterpret_cast<const uint4*>(W2T + n * 128 + k8);
  }
  f32x4 acc[4][4] = {};
  for (int k0 = 0; k0 < 256; k0 += 32) {
#pragma unroll
    for (int qq = 0; qq < 2; ++qq) {
      int idx = qq * 256 + tid;
      int row = idx >> 2, kc = idx & 3;
      GLOAD_LDS16(S + (size_t)(tileM + row) * 256 + k0 + kc * 8, As + idx * 8);
      GLOAD_LDS16(W1T + (size_t)row * 256 + k0 + kc * 8, Bs + idx * 8);
    }
    __syncthreads();
    bf16x8 af[4], bfr[4];
#pragma unroll
    for (int m = 0; m < 4; ++m)
      af[m] = *reinterpret_cast<const bf16x8*>(
          As + (wm * 64 + m * 16 + (lane & 15)) * 32 + (lane >> 4) * 8);
#pragma unroll
    for (int n = 0; n < 4; ++n)
      bfr[n] = *reinterpret_cast<const bf16x8*>(
          Bs + (wn * 64 + n * 16 + (lane & 15)) * 32 + (lane >> 4) * 8);
#pragma unroll
    for (int m = 0; m < 4; ++m)
#pragma unroll
      for (int n = 0; n < 4; ++n)
        acc[m][n] = __builtin_amdgcn_mfma_f32_16x16x32_bf16(af[m], bfr[n], acc[m][n], 0, 0, 0);
    __syncthreads();
  }
  // epilogue 1: leaky(acc + b1f) -> Gs (bf16), all 128 rows
#pragma unroll
  for (int n = 0; n < 4; ++n) {
    const int col = wn * 64 + n * 16 + (lane & 15);
    const float b = b1f[col];
#pragma unroll
    for (int m = 0; m < 4; ++m) {
      const int lr0 = wm * 64 + m * 16 + ((lane >> 4) << 2);
#pragma unroll
      for (int r = 0; r < 4; ++r) {
        float v = acc[m][n][r] + b;
        v = v > 0.f ? v : 0.1f * v;
        Gs[(lr0 + r) * 136 + col] = f2bf(v);
      }
    }
  }
  __syncthreads();
  // epilogue 2: out-tile = Gs @ Ws^T + b2  (each wave: 32 rows)
  const int rr = wave * 32;
#pragma unroll
  for (int cc = 0; cc < 2; ++cc) {
    f32x4 a2 = {};
#pragma unroll
    for (int kk = 0; kk < 4; ++kk) {
      bf16x8 af = *reinterpret_cast<const bf16x8*>(
          Gs + (rr + cc * 16 + (lane & 15)) * 136 + kk * 32 + (lane >> 4) * 8);
      bf16x8 bf = *reinterpret_cast<const bf16x8*>(
          Ws + (lane & 15) * 136 + kk * 32 + (lane >> 4) * 8);
      a2 = __builtin_amdgcn_mfma_f32_16x16x32_bf16(af, bf, a2, 0, 0, 0);
    }
    const int col = lane & 15;
    const int row0 = tileM + rr + cc * 16 + ((lane >> 4) << 2);
#pragma unroll
    for (int r = 0; r < 4; ++r) {
      int row = row0 + r;
      if (row < NROWS) out[(size_t)row * 16 + col] = a2[r] + b2[col];
    }
  }
}

// =============================================================================
extern "C" void kernel_launch(void* const* d_in, const int* in_sizes, int n_in,
                              void* d_out, int out_size, void* d_ws, size_t ws_size,
                              hipStream_t stream) {
  const float* x   = (const float*)d_in[0];
  const int* src0  = (const int*)d_in[1];
  const int* dst0  = (const int*)d_in[2];
  const int* src1  = (const int*)d_in[3];
  const int* dst1  = (const int*)d_in[4];
  const float* Wl  = (const float*)d_in[5];
  const float* bl  = (const float*)d_in[6];
  const float* Wr  = (const float*)d_in[7];
  const float* gma = (const float*)d_in[8];
  const float* bta = (const float*)d_in[9];
  const float* W1  = (const float*)d_in[10];
  const float* b1  = (const float*)d_in[11];
  const float* W2  = (const float*)d_in[12];
  const float* b2  = (const float*)d_in[13];
  float* out = (float*)d_out;
  (void)in_sizes; (void)n_in; (void)out_size; (void)ws_size;

  char* p = (char*)d_ws;
  auto take = [&](size_t bytes) -> void* {
    char* r = p; p += (bytes + 255) & ~(size_t)255; return (void*)r;
  };
  u16* Xb    = (u16*)take((size_t)MP * 256 * 2);   // x bf16; later reused as Hn1
  u16* A     = (u16*)take((size_t)MP * 512 * 2);   // [mean0 | mean1]
  u16* Hn0   = (u16*)take((size_t)MP * 256 * 2);   // layer-0 raw activation
  u16* WcatT = (u16*)take((size_t)2 * 256 * 768 * 2);
  u16* W1T   = (u16*)take(128 * 256 * 2);
  u16* W2T   = (u16*)take(16 * 128 * 2);
  float* bsum  = (float*)take(512 * 4);
  float* scsh  = (float*)take(512 * 4);
  float* foldb = (float*)take(256 * 4);
  float* b1f   = (float*)take(128 * 4);
  float* partial = (float*)take((size_t)NPART * 512 * 4);
  int* hist    = (int*)take((size_t)2 * NPARTS * 4);
  int* offs    = (int*)take((size_t)(2 * NPARTS + 1) * 4);
  int* cursor  = (int*)take((size_t)2 * NPARTS * 4);
  u32* binned  = (u32*)take((size_t)2 * NEDGE * 4);
  u16* Hn1 = Xb;   // alias: Xb free after layer-0 GEMM

  {
    int total = 2 * 256 * 768 + 128 * 256 + 16 * 128 + 512;
    k_prep_w<<<(total + 255) / 256, 256, 0, stream>>>(Wl, Wr, bl, W1, W2,
                                                      WcatT, W1T, W2T, bsum);
  }
  k_prep_x<<<(MP * 32 + 255) / 256, 256, 0, stream>>>(x, Xb);
  hipMemsetAsync(hist, 0, (size_t)2 * NPARTS * 4, stream);
  k_hist<<<dim3(128, 2), 256, 0, stream>>>(dst0, dst1, hist);
  k_scan<<<1, 1024, 0, stream>>>(hist, offs, cursor);
  k_binscatter<<<dim3((NEDGE + BLK_E - 1) / BLK_E, 2), 1024, 0, stream>>>(
      src0, dst0, src1, dst1, cursor, binned);

  // ---- layer 0
  k_agg<<<dim3(NPARTS, 2), 256, 0, stream>>>(offs, binned, Xb, A);
  k_gemm768<<<784, 256, 0, stream>>>(A, Xb, WcatT, bsum, Hn0, partial);
  k_stats<<<256, 256, 0, stream>>>(partial, gma, bta, scsh);
  k_fold_cat<<<256, 256, 0, stream>>>(scsh, bsum, WcatT + (size_t)256 * 768, foldb);

  // ---- layer 1
  k_agg<<<dim3(NPARTS, 2), 256, 0, stream>>>(offs, binned, Hn0, A);
  k_gemm768<<<784, 256, 0, stream>>>(A, Hn0, WcatT + (size_t)256 * 768,
                                     foldb, Hn1, partial);
  k_stats<<<256, 256, 0, stream>>>(partial, gma + 256, bta + 256, scsh);
  k_fold_w1<<<128, 256, 0, stream>>>(scsh, b1, W1T, b1f);

  // ---- fused MLP + output projection
  k_mlp<<<MP / 128, 256, 0, stream>>>(Hn1, W1T, b1f, W2T, b2, out);
}